// Round 1
// baseline (3287.825 us; speedup 1.0000x reference)
//
#include <hip/hip_runtime.h>

constexpr int CB = 512;   // batch
constexpr int CN = 196;   // patches
constexpr int CL = 256;   // tokens
constexpr int CE = 768;   // embed
constexpr int CP = 512;   // probe dim
constexpr int CK = 98;    // top-k

__device__ __forceinline__ unsigned enc_f32(float f) {
    // order-preserving map float -> uint (greater float => greater uint)
    unsigned u = __float_as_uint(f);
    return (u & 0x80000000u) ? ~u : (u | 0x80000000u);
}

// ---------------------------------------------------------------------------
// GEMM: X(M,P) = A(M,E) @ W(E,P) + bias ; n2part[row*4+pt] = partial sum of
// squares over this block's 128 columns. M is a multiple of 64.
// Block: 256 threads, tile 64 rows x 128 cols, BK=16.
// ---------------------------------------------------------------------------
__global__ __launch_bounds__(256) void gemm_proj(
    const float* __restrict__ A, const float* __restrict__ W,
    const float* __restrict__ bias, float* __restrict__ X,
    float* __restrict__ n2part)
{
    __shared__ float As[16][68];   // k-major, padded stride 68 (16B aligned)
    __shared__ float Ws[16][128];

    const int pt = blockIdx.x;           // 0..3
    const int m0 = blockIdx.y * 64;
    const int p0 = pt * 128;
    const int t  = threadIdx.x;
    const int tx = t & 15, ty = t >> 4;

    float acc[4][8];
#pragma unroll
    for (int i = 0; i < 4; ++i)
#pragma unroll
        for (int j = 0; j < 8; ++j) acc[i][j] = 0.f;

    const int arow = t >> 2;             // 0..63
    const int akc  = (t & 3) * 4;        // 0,4,8,12
    const int wrow = t >> 5;             // 0..7
    const int wcol = (t & 31) * 4;       // 0..124
    const float* Ap = A + (size_t)(m0 + arow) * CE + akc;
    const float* Wp = W + (size_t)wrow * CP + p0 + wcol;

    for (int k0 = 0; k0 < CE; k0 += 16) {
        float4 av  = *(const float4*)(Ap + k0);
        float4 wv0 = *(const float4*)(Wp + (size_t)k0 * CP);
        float4 wv1 = *(const float4*)(Wp + (size_t)(k0 + 8) * CP);
        __syncthreads();
        As[akc + 0][arow] = av.x;
        As[akc + 1][arow] = av.y;
        As[akc + 2][arow] = av.z;
        As[akc + 3][arow] = av.w;
        *(float4*)&Ws[wrow][wcol]     = wv0;
        *(float4*)&Ws[wrow + 8][wcol] = wv1;
        __syncthreads();
#pragma unroll
        for (int k = 0; k < 16; ++k) {
            float4 a4 = *(const float4*)&As[k][ty * 4];
            float4 b0 = *(const float4*)&Ws[k][tx * 4];
            float4 b1 = *(const float4*)&Ws[k][64 + tx * 4];
            float ar[4] = {a4.x, a4.y, a4.z, a4.w};
            float br[8] = {b0.x, b0.y, b0.z, b0.w, b1.x, b1.y, b1.z, b1.w};
#pragma unroll
            for (int i = 0; i < 4; ++i)
#pragma unroll
                for (int j = 0; j < 8; ++j)
                    acc[i][j] = fmaf(ar[i], br[j], acc[i][j]);
        }
    }

    // epilogue: bias, store X, per-row sumsq partial
    const int c0 = p0 + tx * 4;
    const int c1 = p0 + 64 + tx * 4;
    float bv[8];
#pragma unroll
    for (int j = 0; j < 4; ++j) { bv[j] = bias[c0 + j]; bv[4 + j] = bias[c1 + j]; }

    float rs[4];
#pragma unroll
    for (int i = 0; i < 4; ++i) {
        const int row = m0 + ty * 4 + i;
        float4 x0, x1;
        float s = 0.f, v;
        v = acc[i][0] + bv[0]; x0.x = v; s = fmaf(v, v, s);
        v = acc[i][1] + bv[1]; x0.y = v; s = fmaf(v, v, s);
        v = acc[i][2] + bv[2]; x0.z = v; s = fmaf(v, v, s);
        v = acc[i][3] + bv[3]; x0.w = v; s = fmaf(v, v, s);
        v = acc[i][4] + bv[4]; x1.x = v; s = fmaf(v, v, s);
        v = acc[i][5] + bv[5]; x1.y = v; s = fmaf(v, v, s);
        v = acc[i][6] + bv[6]; x1.z = v; s = fmaf(v, v, s);
        v = acc[i][7] + bv[7]; x1.w = v; s = fmaf(v, v, s);
        *(float4*)(X + (size_t)row * CP + c0) = x0;
        *(float4*)(X + (size_t)row * CP + c1) = x1;
        rs[i] = s;
    }
    __syncthreads();
    float* red = &As[0][0];   // 16*68 = 1088 floats >= 64*16
#pragma unroll
    for (int i = 0; i < 4; ++i) red[(ty * 4 + i) * 16 + tx] = rs[i];
    __syncthreads();
    if (t < 64) {
        float s = 0.f;
#pragma unroll
        for (int q = 0; q < 16; ++q) s += red[t * 16 + q];
        n2part[(size_t)(m0 + t) * 4 + pt] = s;
    }
}

// ---------------------------------------------------------------------------
// invn[i] = 1 / max(sqrt(sum of 4 partials), 1e-12)
// ---------------------------------------------------------------------------
__global__ void inv_norm(const float* __restrict__ n2part,
                         float* __restrict__ invn, int M)
{
    int i = blockIdx.x * 256 + threadIdx.x;
    if (i < M) {
        const float* p = n2part + (size_t)i * 4;
        float s = (p[0] + p[1]) + (p[2] + p[3]);
        float n = fmaxf(sqrtf(s), 1e-12f);
        invn[i] = 1.f / n;
    }
}

// ---------------------------------------------------------------------------
// sim = (pf . tf) * invp * invt ; masked running max over tokens into
// scores[b*N+row] as order-preserving uint via atomicMax (init = 0).
// Block: 256 threads, tile 64 pf-rows x 64 tokens, K chunks of 32.
// grid: x = rt*4+tt (16), y = batch.
// ---------------------------------------------------------------------------
__global__ __launch_bounds__(256) void sim_max(
    const float* __restrict__ pf, const float* __restrict__ tfm,
    const float* __restrict__ invp, const float* __restrict__ invt,
    const int* __restrict__ amask, unsigned* __restrict__ scores)
{
    __shared__ float Ps[32][68];
    __shared__ float Ts[32][68];

    const int b  = blockIdx.y;
    const int rt = blockIdx.x >> 2;
    const int tt = blockIdx.x & 3;
    const int r0 = rt * 64, tok0 = tt * 64;
    const int t  = threadIdx.x;
    const int tx = t & 15, ty = t >> 4;

    const float* Pb = pf  + (size_t)b * CN * CP;
    const float* Tb = tfm + (size_t)b * CL * CP;

    float acc[4][4];
#pragma unroll
    for (int i = 0; i < 4; ++i)
#pragma unroll
        for (int j = 0; j < 4; ++j) acc[i][j] = 0.f;

    const int srow = t >> 3;             // 0..31
    const int skc  = (t & 7) * 4;        // 0..28
    const int pr0 = min(r0 + srow, CN - 1);        // clamp ragged pf rows
    const int pr1 = min(r0 + srow + 32, CN - 1);

    for (int kc = 0; kc < CP; kc += 32) {
        float4 pv0 = *(const float4*)(Pb + (size_t)pr0 * CP + kc + skc);
        float4 pv1 = *(const float4*)(Pb + (size_t)pr1 * CP + kc + skc);
        float4 tv0 = *(const float4*)(Tb + (size_t)(tok0 + srow) * CP + kc + skc);
        float4 tv1 = *(const float4*)(Tb + (size_t)(tok0 + srow + 32) * CP + kc + skc);
        __syncthreads();
        Ps[skc + 0][srow] = pv0.x; Ps[skc + 1][srow] = pv0.y;
        Ps[skc + 2][srow] = pv0.z; Ps[skc + 3][srow] = pv0.w;
        Ps[skc + 0][srow + 32] = pv1.x; Ps[skc + 1][srow + 32] = pv1.y;
        Ps[skc + 2][srow + 32] = pv1.z; Ps[skc + 3][srow + 32] = pv1.w;
        Ts[skc + 0][srow] = tv0.x; Ts[skc + 1][srow] = tv0.y;
        Ts[skc + 2][srow] = tv0.z; Ts[skc + 3][srow] = tv0.w;
        Ts[skc + 0][srow + 32] = tv1.x; Ts[skc + 1][srow + 32] = tv1.y;
        Ts[skc + 2][srow + 32] = tv1.z; Ts[skc + 3][srow + 32] = tv1.w;
        __syncthreads();
#pragma unroll
        for (int k = 0; k < 32; ++k) {
            float4 a4 = *(const float4*)&Ps[k][ty * 4];
            float4 c4 = *(const float4*)&Ts[k][tx * 4];
            float ar[4] = {a4.x, a4.y, a4.z, a4.w};
            float cr[4] = {c4.x, c4.y, c4.z, c4.w};
#pragma unroll
            for (int i = 0; i < 4; ++i)
#pragma unroll
                for (int j = 0; j < 4; ++j)
                    acc[i][j] = fmaf(ar[i], cr[j], acc[i][j]);
        }
    }

    // epilogue: scale by inverse norms, mask, max over this thread's 4 tokens
    const int tokc = tok0 + tx * 4;
    float it[4]; int mk[4];
#pragma unroll
    for (int j = 0; j < 4; ++j) {
        it[j] = invt[(size_t)b * CL + tokc + j];
        mk[j] = amask[(size_t)b * CL + tokc + j];
    }
    float mx[4];
#pragma unroll
    for (int i = 0; i < 4; ++i) {
        const int row = r0 + ty * 4 + i;
        float m = -3.402823466e38f;
        if (row < CN) {
            const float ip = invp[(size_t)b * CN + row];
#pragma unroll
            for (int j = 0; j < 4; ++j) {
                if (mk[j]) {
                    float v = acc[i][j] * ip * it[j];
                    m = fmaxf(m, v);
                }
            }
        }
        mx[i] = m;
    }
    __syncthreads();
    float* red = &Ps[0][0];  // 32*68 floats >= 64*16
#pragma unroll
    for (int i = 0; i < 4; ++i) red[(ty * 4 + i) * 16 + tx] = mx[i];
    __syncthreads();
    if (t < 64) {
        const int row = r0 + t;
        if (row < CN) {
            float m = -3.402823466e38f;
#pragma unroll
            for (int q = 0; q < 16; ++q) m = fmaxf(m, red[t * 16 + q]);
            atomicMax(&scores[(size_t)b * CN + row], enc_f32(m));
        }
    }
}

// ---------------------------------------------------------------------------
// Per batch: rank each of 196 scores (desc value, asc index tie-break == jax
// top_k), select rank<K, emit selected indices in ascending index order.
// ---------------------------------------------------------------------------
__global__ __launch_bounds__(256) void topk_sel(
    const unsigned* __restrict__ scores, int* __restrict__ sel)
{
    __shared__ unsigned ky[CN];
    __shared__ int flg[CN];
    const int b = blockIdx.x, t = threadIdx.x;
    if (t < CN) ky[t] = scores[(size_t)b * CN + t];
    __syncthreads();
    int f = 0;
    if (t < CN) {
        const unsigned kt = ky[t];
        int rank = 0;
        for (int j = 0; j < CN; ++j) {
            const unsigned kj = ky[j];
            rank += (int)((kj > kt) | ((kj == kt) & (j < t)));
        }
        f = (rank < CK) ? 1 : 0;
        flg[t] = f;
    }
    __syncthreads();
    if (t < CN && f) {
        int pos = 0;
        for (int j = 0; j < t; ++j) pos += flg[j];
        sel[(size_t)b * CK + pos] = t;
    }
}

// ---------------------------------------------------------------------------
// out[b,0,:] = state[b,0,:]; out[b,1+p,:] = state[b,1+sel[b,p],:]
// one block per output row, 192 threads x float4 = 768 floats
// ---------------------------------------------------------------------------
__global__ __launch_bounds__(192) void gather_out(
    const float* __restrict__ state, const int* __restrict__ sel,
    float* __restrict__ out)
{
    const int bid = blockIdx.x;
    const int b = bid / (CK + 1);
    const int r = bid - b * (CK + 1);
    int src = 0;
    if (r > 0) src = 1 + sel[(size_t)b * CK + (r - 1)];
    const float4* s = (const float4*)(state + ((size_t)b * (CN + 1) + src) * CE);
    float4* o = (float4*)(out + ((size_t)b * (CK + 1) + r) * CE);
    o[threadIdx.x] = s[threadIdx.x];
}

extern "C" void kernel_launch(void* const* d_in, const int* in_sizes, int n_in,
                              void* d_out, int out_size, void* d_ws, size_t ws_size,
                              hipStream_t stream) {
    const float* patch = (const float*)d_in[0];   // (B,N,E)
    const float* state = (const float*)d_in[1];   // (B,N+1,E)
    const float* token = (const float*)d_in[2];   // (B,L,E)
    const float* Wpp   = (const float*)d_in[3];   // (E,P)
    const float* bpp   = (const float*)d_in[4];   // (P)
    const float* Wtp   = (const float*)d_in[5];   // (E,P)
    const float* btp   = (const float*)d_in[6];   // (P)
    const int*   amask = (const int*)d_in[7];     // (B,L)
    float* out = (float*)d_out;                   // (B,K+1,E)

    const size_t MN = (size_t)CB * CN;   // 100352
    const size_t ML = (size_t)CB * CL;   // 131072

    char* w = (char*)d_ws;
    unsigned* scores = (unsigned*)w; w += MN * 4;
    float* n2p  = (float*)w; w += MN * 4 * 4;
    float* n2t  = (float*)w; w += ML * 4 * 4;
    float* invp = (float*)w; w += MN * 4;
    float* invt = (float*)w; w += ML * 4;
    int*   sel  = (int*)w;   w += (size_t)CB * CK * 4;
    float* pf   = (float*)w; w += MN * CP * 4;
    float* tf   = (float*)w; w += ML * CP * 4;

    hipMemsetAsync(scores, 0, MN * 4, stream);  // 0 == -inf sentinel in enc_f32 order

    gemm_proj<<<dim3(4, MN / 64), 256, 0, stream>>>(patch, Wpp, bpp, pf, n2p);
    gemm_proj<<<dim3(4, ML / 64), 256, 0, stream>>>(token, Wtp, btp, tf, n2t);
    inv_norm<<<(int)((MN + 255) / 256), 256, 0, stream>>>(n2p, invp, (int)MN);
    inv_norm<<<(int)((ML + 255) / 256), 256, 0, stream>>>(n2t, invt, (int)ML);
    sim_max<<<dim3(16, CB), 256, 0, stream>>>(pf, tf, invp, invt, amask, scores);
    topk_sel<<<CB, 256, 0, stream>>>(scores, sel);
    gather_out<<<CB * (CK + 1), 192, 0, stream>>>(state, sel, out);
}